// Round 11
// baseline (159.833 us; speedup 1.0000x reference)
//
#include <hip/hip_runtime.h>

// ---------------------------------------------------------------------------
// FEM assembly: dense stiffness (ndof x ndof) + residual (ndof).
// Structure (2 graph nodes):
//   N0 fill_kernel: PLAIN-store (non-NT) grid-stride float4 zero fill of the
//      whole output. Tests the last untested cell: r7's custom fill used NT
//      stores (bypass L2 -> ~4.4 TB/s); runtime memset ~4.8; plain-store
//      pure fill may match fillBufferAligned's rate.
//   N1 fused_kernel (unchanged from r10, verified): per-block LDS fixed-dof
//      bitmap, then element 6x6 scatter (skip fixed rows) + traction atomics
//      (skip fixed dofs) + diag=1 + last-wins resid.
// ---------------------------------------------------------------------------

typedef float fx4 __attribute__((ext_vector_type(4)));

__global__ __launch_bounds__(256) void fill_kernel(fx4* __restrict__ p,
                                                   long n4) {
    const long stride = (long)gridDim.x * 256;
    long i = (long)blockIdx.x * 256 + threadIdx.x;
    const fx4 z = (fx4){0.f, 0.f, 0.f, 0.f};
    for (; i < n4; i += stride) p[i] = z;   // plain stores, through L2
}

__global__ __launch_bounds__(256) void fused_kernel(
        const float* __restrict__ x, const float* __restrict__ y,
        const int* __restrict__ connect, const float* __restrict__ mat,
        const int* __restrict__ dl_elem, const int* __restrict__ dl_face,
        const float* __restrict__ dl_tx, const float* __restrict__ dl_ty,
        const int* __restrict__ fix_node, const int* __restrict__ fix_dof,
        const float* __restrict__ fix_val,
        float* __restrict__ stiff, float* __restrict__ resid,
        int nelem, int ndload, int nfix, int nnode) {
    __shared__ unsigned int bm[512];          // fixed-dof bitmap, ndof<=16384
    const int ndof = 2 * nnode;
    const int nw = (ndof + 31) >> 5;

    // redundant per-block bitmap build (200 fixes, L2-hot)
    for (int i = threadIdx.x; i < nw; i += 256) bm[i] = 0u;
    __syncthreads();
    for (int i = threadIdx.x; i < nfix; i += 256) {
        const int rw = 2 * fix_node[i] + fix_dof[i];
        atomicOr(&bm[rw >> 5], 1u << (rw & 31));
    }
    __syncthreads();

    const int tid = blockIdx.x * 256 + threadIdx.x;

    if (tid < nelem) {
        const int e = tid;
        const int a = connect[3 * e + 0];
        const int b = connect[3 * e + 1];
        const int c = connect[3 * e + 2];

        const float xa = x[a], xb = x[b], xc = x[c];
        const float ya = y[a], yb = y[b], yc = y[c];

        const float den_a = (ya - yb) * (xc - xb) - (xa - xb) * (yc - yb);
        const float den_b = (yb - yc) * (xa - xc) - (xb - xc) * (ya - yc);
        const float den_c = (yc - ya) * (xb - xa) - (xc - xa) * (yb - ya);

        const float nax = -(yc - yb) / den_a;
        const float nay =  (xc - xb) / den_a;
        const float nbx = -(ya - yc) / den_b;
        const float nby =  (xa - xc) / den_b;
        const float ncx = -(yb - ya) / den_c;
        const float ncy =  (xb - xa) / den_c;

        const float area = 0.5f * fabsf((xb - xa) * (yc - ya) -
                                        (xc - xa) * (yb - ya));

        float nu, E;
        if (mat[e] > 0.5f) { nu = 0.33f; E = 69.0f; }   // aluminium
        else               { nu = 0.30f; E = 200.0f; }  // steel
        const float cc  = E / ((1.0f + nu) * (1.0f - 2.0f * nu));
        const float d00 = cc * (1.0f - nu);
        const float d01 = cc * nu;
        const float d22 = cc * (1.0f - 2.0f * nu) * 0.5f;

        const float B0[6] = { nax, 0.f, nbx, 0.f, ncx, 0.f };
        const float B1[6] = { 0.f, nay, 0.f, nby, 0.f, ncy };
        const float B2[6] = { nay, nax, nby, nbx, ncy, ncx };

        float C0[6], C1[6], C2[6];
#pragma unroll
        for (int j = 0; j < 6; ++j) {
            C0[j] = d00 * B0[j] + d01 * B1[j];
            C1[j] = d01 * B0[j] + d00 * B1[j];
            C2[j] = d22 * B2[j];
        }

        const int dof[6] = { 2 * a, 2 * a + 1, 2 * b, 2 * b + 1,
                             2 * c, 2 * c + 1 };

#pragma unroll
        for (int i = 0; i < 6; ++i) {
            const bool fixed = (bm[dof[i] >> 5] >> (dof[i] & 31)) & 1u;
            if (fixed) continue;            // fixed row: contribution dropped
            float* rowp = stiff + (size_t)dof[i] * (size_t)ndof;
#pragma unroll
            for (int j = 0; j < 6; ++j) {
                const float kij = area * (B0[i] * C0[j] + B1[i] * C1[j] +
                                          B2[i] * C2[j]);
                atomicAdd(rowp + dof[j], kij);
            }
        }
        return;
    }

    const int t2 = tid - nelem;
    if (t2 < ndload) {
        const int e = dl_elem[t2];
        const int f = dl_face[t2];
        const int f2 = (f == 0) ? 1 : (f == 1 ? 2 : 0);   // pointer = [1,2,0]
        const int a = connect[3 * e + f];
        const int b = connect[3 * e + f2];
        const float dx = x[a] - x[b];
        const float dy = y[a] - y[b];
        const float hl = 0.5f * sqrtf(dx * dx + dy * dy);
        const float vx = dl_tx[t2] * hl;
        const float vy = dl_ty[t2] * hl;
        const int dofs[4] = { 2 * a, 2 * a + 1, 2 * b, 2 * b + 1 };
        const float vals[4] = { vx, vy, vx, vy };
#pragma unroll
        for (int k = 0; k < 4; ++k) {
            const int rw = dofs[k];
            const bool fixed = (bm[rw >> 5] >> (rw & 31)) & 1u;
            if (!fixed) atomicAdd(&resid[rw], vals[k]);  // fixed: set() wins
        }
        return;
    }

    const int t3 = t2 - ndload;
    if (t3 < nfix) {
        const int rw = 2 * fix_node[t3] + fix_dof[t3];
        stiff[(size_t)rw * (size_t)ndof + rw] = 1.0f;    // dups: same value
        // last-occurrence-wins (NumPy fancy-assignment semantics)
        bool last = true;
        for (int j = t3 + 1; j < nfix; ++j) {
            if (2 * fix_node[j] + fix_dof[j] == rw) { last = false; break; }
        }
        if (last) resid[rw] = fix_val[t3];
    }
}

extern "C" void kernel_launch(void* const* d_in, const int* in_sizes, int n_in,
                              void* d_out, int out_size, void* d_ws, size_t ws_size,
                              hipStream_t stream) {
    const float* xcoord   = (const float*)d_in[0];
    const float* ycoord   = (const float*)d_in[1];
    const int*   connect  = (const int*)d_in[2];
    const float* emat     = (const float*)d_in[3];
    const int*   dl_elem  = (const int*)d_in[4];
    const int*   dl_face  = (const int*)d_in[5];
    const float* dl_tx    = (const float*)d_in[6];
    const float* dl_ty    = (const float*)d_in[7];
    const int*   fix_node = (const int*)d_in[8];
    const int*   fix_dof  = (const int*)d_in[9];
    const float* fix_val  = (const float*)d_in[10];

    const int nnode  = in_sizes[0];
    const int ndof   = 2 * nnode;
    const int nelem  = in_sizes[3];
    const int ndload = in_sizes[4];
    const int nfix   = in_sizes[8];

    float* stiff = (float*)d_out;
    float* resid = stiff + (size_t)ndof * (size_t)ndof;

    // N0: 576 MB zero write via plain-store custom fill (out_size % 4 == 0
    // here; guard the remainder scalar-wise just in case)
    {
        const long total = (long)out_size;
        const long n4 = total >> 2;
        fill_kernel<<<4096, 256, 0, stream>>>((fx4*)d_out, n4);
        // tail (0..3 floats) — covered by fused kernel ordering only if zero;
        // out_size = ndof*ndof + ndof is divisible by 4 for even ndof.
    }

    // N1: everything else in one ordinary kernel
    {
        const int total = nelem + ndload + nfix;
        const int blocks = (total + 255) / 256;
        fused_kernel<<<blocks, 256, 0, stream>>>(
            xcoord, ycoord, connect, emat, dl_elem, dl_face, dl_tx, dl_ty,
            fix_node, fix_dof, fix_val, stiff, resid,
            nelem, ndload, nfix, nnode);
    }
}

// Round 12
// 128.347 us; speedup vs baseline: 1.2453x; 1.2453x over previous
//
#include <hip/hip_runtime.h>

// ---------------------------------------------------------------------------
// FEM assembly: dense stiffness (ndof x ndof) + residual (ndof).
// FINAL structure (2 graph nodes) — session best, 128.3 us:
//   N0 hipMemsetAsync(d_out): the 576 MB zero write (~120 us in-graph).
//      Measured r7/r11: every custom fill (NT or plain stores) is 25-31 us
//      SLOWER than the runtime memset; fused-logic writers cap at ~4.4 TB/s.
//   N1 ONE kernel: per-block LDS fixed-dof bitmap (redundant build removes
//      any grid-wide dependency), then by global tid:
//        [0,nelem)      element 6x6 scatter, skipping fixed rows (bitmap)
//        [.., +ndload)  traction atomics into resid, skipping fixed dofs
//        [.., +nfix)    diag=1 + last-occurrence-wins resid[rw]=fix_val
// Equivalence to reference BCs: dropping fixed-row contributions == zeroing
// the row after assembly; skipping traction adds on fixed dofs == set()
// overwriting them. Races benign (dup diags store the same 1.0).
// ---------------------------------------------------------------------------

__global__ __launch_bounds__(256) void fused_kernel(
        const float* __restrict__ x, const float* __restrict__ y,
        const int* __restrict__ connect, const float* __restrict__ mat,
        const int* __restrict__ dl_elem, const int* __restrict__ dl_face,
        const float* __restrict__ dl_tx, const float* __restrict__ dl_ty,
        const int* __restrict__ fix_node, const int* __restrict__ fix_dof,
        const float* __restrict__ fix_val,
        float* __restrict__ stiff, float* __restrict__ resid,
        int nelem, int ndload, int nfix, int nnode) {
    __shared__ unsigned int bm[512];          // fixed-dof bitmap, ndof<=16384
    const int ndof = 2 * nnode;
    const int nw = (ndof + 31) >> 5;

    // redundant per-block bitmap build (200 fixes, L2-hot)
    for (int i = threadIdx.x; i < nw; i += 256) bm[i] = 0u;
    __syncthreads();
    for (int i = threadIdx.x; i < nfix; i += 256) {
        const int rw = 2 * fix_node[i] + fix_dof[i];
        atomicOr(&bm[rw >> 5], 1u << (rw & 31));
    }
    __syncthreads();

    const int tid = blockIdx.x * 256 + threadIdx.x;

    if (tid < nelem) {
        const int e = tid;
        const int a = connect[3 * e + 0];
        const int b = connect[3 * e + 1];
        const int c = connect[3 * e + 2];

        const float xa = x[a], xb = x[b], xc = x[c];
        const float ya = y[a], yb = y[b], yc = y[c];

        const float den_a = (ya - yb) * (xc - xb) - (xa - xb) * (yc - yb);
        const float den_b = (yb - yc) * (xa - xc) - (xb - xc) * (ya - yc);
        const float den_c = (yc - ya) * (xb - xa) - (xc - xa) * (yb - ya);

        const float nax = -(yc - yb) / den_a;
        const float nay =  (xc - xb) / den_a;
        const float nbx = -(ya - yc) / den_b;
        const float nby =  (xa - xc) / den_b;
        const float ncx = -(yb - ya) / den_c;
        const float ncy =  (xb - xa) / den_c;

        const float area = 0.5f * fabsf((xb - xa) * (yc - ya) -
                                        (xc - xa) * (yb - ya));

        float nu, E;
        if (mat[e] > 0.5f) { nu = 0.33f; E = 69.0f; }   // aluminium
        else               { nu = 0.30f; E = 200.0f; }  // steel
        const float cc  = E / ((1.0f + nu) * (1.0f - 2.0f * nu));
        const float d00 = cc * (1.0f - nu);
        const float d01 = cc * nu;
        const float d22 = cc * (1.0f - 2.0f * nu) * 0.5f;

        const float B0[6] = { nax, 0.f, nbx, 0.f, ncx, 0.f };
        const float B1[6] = { 0.f, nay, 0.f, nby, 0.f, ncy };
        const float B2[6] = { nay, nax, nby, nbx, ncy, ncx };

        float C0[6], C1[6], C2[6];
#pragma unroll
        for (int j = 0; j < 6; ++j) {
            C0[j] = d00 * B0[j] + d01 * B1[j];
            C1[j] = d01 * B0[j] + d00 * B1[j];
            C2[j] = d22 * B2[j];
        }

        const int dof[6] = { 2 * a, 2 * a + 1, 2 * b, 2 * b + 1,
                             2 * c, 2 * c + 1 };

#pragma unroll
        for (int i = 0; i < 6; ++i) {
            const bool fixed = (bm[dof[i] >> 5] >> (dof[i] & 31)) & 1u;
            if (fixed) continue;            // fixed row: contribution dropped
            float* rowp = stiff + (size_t)dof[i] * (size_t)ndof;
#pragma unroll
            for (int j = 0; j < 6; ++j) {
                const float kij = area * (B0[i] * C0[j] + B1[i] * C1[j] +
                                          B2[i] * C2[j]);
                atomicAdd(rowp + dof[j], kij);
            }
        }
        return;
    }

    const int t2 = tid - nelem;
    if (t2 < ndload) {
        const int e = dl_elem[t2];
        const int f = dl_face[t2];
        const int f2 = (f == 0) ? 1 : (f == 1 ? 2 : 0);   // pointer = [1,2,0]
        const int a = connect[3 * e + f];
        const int b = connect[3 * e + f2];
        const float dx = x[a] - x[b];
        const float dy = y[a] - y[b];
        const float hl = 0.5f * sqrtf(dx * dx + dy * dy);
        const float vx = dl_tx[t2] * hl;
        const float vy = dl_ty[t2] * hl;
        const int dofs[4] = { 2 * a, 2 * a + 1, 2 * b, 2 * b + 1 };
        const float vals[4] = { vx, vy, vx, vy };
#pragma unroll
        for (int k = 0; k < 4; ++k) {
            const int rw = dofs[k];
            const bool fixed = (bm[rw >> 5] >> (rw & 31)) & 1u;
            if (!fixed) atomicAdd(&resid[rw], vals[k]);  // fixed: set() wins
        }
        return;
    }

    const int t3 = t2 - ndload;
    if (t3 < nfix) {
        const int rw = 2 * fix_node[t3] + fix_dof[t3];
        stiff[(size_t)rw * (size_t)ndof + rw] = 1.0f;    // dups: same value
        // last-occurrence-wins (NumPy fancy-assignment semantics)
        bool last = true;
        for (int j = t3 + 1; j < nfix; ++j) {
            if (2 * fix_node[j] + fix_dof[j] == rw) { last = false; break; }
        }
        if (last) resid[rw] = fix_val[t3];
    }
}

extern "C" void kernel_launch(void* const* d_in, const int* in_sizes, int n_in,
                              void* d_out, int out_size, void* d_ws, size_t ws_size,
                              hipStream_t stream) {
    const float* xcoord   = (const float*)d_in[0];
    const float* ycoord   = (const float*)d_in[1];
    const int*   connect  = (const int*)d_in[2];
    const float* emat     = (const float*)d_in[3];
    const int*   dl_elem  = (const int*)d_in[4];
    const int*   dl_face  = (const int*)d_in[5];
    const float* dl_tx    = (const float*)d_in[6];
    const float* dl_ty    = (const float*)d_in[7];
    const int*   fix_node = (const int*)d_in[8];
    const int*   fix_dof  = (const int*)d_in[9];
    const float* fix_val  = (const float*)d_in[10];

    const int nnode  = in_sizes[0];
    const int ndof   = 2 * nnode;
    const int nelem  = in_sizes[3];
    const int ndload = in_sizes[4];
    const int nfix   = in_sizes[8];

    float* stiff = (float*)d_out;
    float* resid = stiff + (size_t)ndof * (size_t)ndof;

    // N0: the 576 MB zero write (structural floor, ~120 us in-graph)
    (void)hipMemsetAsync(d_out, 0, (size_t)out_size * sizeof(float), stream);

    // N1: everything else in one ordinary kernel
    {
        const int total = nelem + ndload + nfix;
        const int blocks = (total + 255) / 256;
        fused_kernel<<<blocks, 256, 0, stream>>>(
            xcoord, ycoord, connect, emat, dl_elem, dl_face, dl_tx, dl_ty,
            fix_node, fix_dof, fix_val, stiff, resid,
            nelem, ndload, nfix, nnode);
    }
}